// Round 2
// 93.444 us; speedup vs baseline: 1.0045x; 1.0045x over previous
//
#include <hip/hip_runtime.h>
#include <math.h>

typedef float f32x4 __attribute__((ext_vector_type(4)));

// D[k][n] = 0.5*cos(pi*(2n+1)k/16), row 0 scaled by 1/sqrt(2).
__device__ __forceinline__ float dctD(int k, int n) {
    const float c[9] = {1.0f, 0.98078528040323043f, 0.92387953251128674f,
                        0.83146961230254524f, 0.70710678118654752f,
                        0.55557023301960218f, 0.38268343236508977f,
                        0.19509032201612825f, 0.0f};
    int m = ((2 * n + 1) * k) & 31;   // cos(m*pi/16), periodic 32
    float s = 1.0f;
    if (m > 16) m = 32 - m;
    if (m > 8) { m = 16 - m; s = -1.0f; }
    float scale = (k == 0) ? 0.35355339059327373f : 0.5f;
    return scale * s * c[m];
}

__device__ __forceinline__ float sigmoidf(float a) {
    return 1.0f / (1.0f + expf(-a));
}

// Workspace layout (floats):
//   feat : [0, 65536)          feat[f*1024 + t],  t = br*32+bc
//   gpart: [65536, 67584)      gpart[wg*64 + c] per-workgroup channel sums
//   plane: [67584, 133120)     the single 256x256 output plane (row-major)
#define WS_FEAT   0
#define WS_GPART  65536
#define WS_PLANE  67584

// 32 workgroups x 256 threads; thread (b = tid&31, r = tid>>5) handles row r
// of local block b. Block t = wg*32 + b.
__global__ __launch_bounds__(256) void dct_kernel(const float* __restrict__ x,
                                                  float* __restrict__ feat,
                                                  float* __restrict__ gpart) {
    __shared__ float Ds[64];
    __shared__ float xs[32][65];   // +1 pad: conflict-free across b
    __shared__ float red[4][64];
    int tid = threadIdx.x;
    if (tid < 64) Ds[tid] = dctD(tid >> 3, tid & 7);
    int b = tid & 31, r = tid >> 5;
    int t = blockIdx.x * 32 + b;
    int br = t >> 5, bc = t & 31;

    // load pixel row r of block b: 8 HWC pixels = 24 floats = 6 float4, contiguous
    // per lane -> wave covers contiguous 3 KB. Extract channel 0 (every 3rd).
    const float4* xrow4 = (const float4*)(x + ((br * 8 + r) * 256 + bc * 8) * 3);
    float4 v0 = xrow4[0], v1 = xrow4[1], v2 = xrow4[2];
    float4 v3 = xrow4[3], v4 = xrow4[4], v5 = xrow4[5];
    xs[b][r * 8 + 0] = v0.x;  xs[b][r * 8 + 1] = v0.w;
    xs[b][r * 8 + 2] = v1.z;  xs[b][r * 8 + 3] = v2.y;
    xs[b][r * 8 + 4] = v3.x;  xs[b][r * 8 + 5] = v3.w;
    xs[b][r * 8 + 6] = v4.z;  xs[b][r * 8 + 7] = v5.y;
    __syncthreads();

    // tmp row r: tr[l] = sum_k D[r][k] * xs[b][k*8+l]
    float tr[8];
    #pragma unroll
    for (int l = 0; l < 8; l++) tr[l] = 0.f;
    #pragma unroll
    for (int k = 0; k < 8; k++) {
        float d = Ds[r * 8 + k];
        #pragma unroll
        for (int l = 0; l < 8; l++) tr[l] += d * xs[b][k * 8 + l];
    }
    // dct row r: o[j] = sum_l tr[l] * D[j][l];  channel c = r*8+j
    float o[8];
    #pragma unroll
    for (int j = 0; j < 8; j++) {
        float s = 0.f;
        #pragma unroll
        for (int l = 0; l < 8; l++) s += tr[l] * Ds[j * 8 + l];
        o[j] = s;
        feat[(r * 8 + j) * 1024 + t] = s;   // lanes: b consecutive -> coalesced
    }
    __syncthreads();                         // all xs reads done
    #pragma unroll
    for (int j = 0; j < 8; j++) xs[b][r * 8 + j] = o[j];   // xs[b][c] = dct value
    __syncthreads();

    // per-workgroup channel sums (for SE squeeze)
    int c = tid & 63, qg = tid >> 6;
    float s = 0.f;
    #pragma unroll
    for (int bb = 0; bb < 8; bb++) s += xs[qg * 8 + bb][c];
    red[qg][c] = s;
    __syncthreads();
    if (tid < 64)
        gpart[blockIdx.x * 64 + tid] =
            red[0][tid] + red[1][tid] + red[2][tid] + red[3][tid];
}

// 32 workgroups x 256 threads: wg tg handles blocks t = tg*32 + b (b = tid&31).
// Computes the SE MLP + spatial gate + IDCT ONCE and writes the single
// 256x256 plane into workspace. Latency-bound but tiny (runs on 32 CUs).
__global__ __launch_bounds__(256) void plane_kernel(const float* __restrict__ feat,
                                                    const float* __restrict__ gpart,
                                                    const float* __restrict__ fc1_w,
                                                    const float* __restrict__ fc1_b,
                                                    const float* __restrict__ fc2_w,
                                                    const float* __restrict__ fc2_b,
                                                    const float* __restrict__ sse_w,
                                                    const float* __restrict__ sse_b,
                                                    float* __restrict__ plane) {
    __shared__ float Ds[64], sw[64], sq[64], sc[64], h[32], spat[32];
    __shared__ float redp[8][33];
    __shared__ float tmls[32][65];
    int tid = threadIdx.x;
    int tg = blockIdx.x;

    if (tid < 64) {
        Ds[tid] = dctD(tid >> 3, tid & 7);
        sw[tid] = sse_w[tid];
        float s = 0.f;
        #pragma unroll
        for (int w = 0; w < 32; w++) s += gpart[w * 64 + tid];
        sq[tid] = s * (1.0f / 1024.0f);
    }
    __syncthreads();
    if (tid < 32) {
        float a = fc1_b[tid];
        #pragma unroll 8
        for (int cc = 0; cc < 64; cc++) a += sq[cc] * fc1_w[tid * 64 + cc];
        h[tid] = fmaxf(a, 0.f);
    }
    __syncthreads();
    if (tid < 64) {
        float a = fc2_b[tid];
        #pragma unroll 8
        for (int rr = 0; rr < 32; rr++) a += h[rr] * fc2_w[tid * 32 + rr];
        sc[tid] = sigmoidf(a);
    }

    int b = tid & 31, r = tid >> 5;
    int t = tg * 32 + b;

    // load feat row r of block b (coalesced: lanes span consecutive t)
    float gr[8];
    #pragma unroll
    for (int l = 0; l < 8; l++) gr[l] = feat[(r * 8 + l) * 1024 + t];
    // spatial dot partial for this row
    float sp = 0.f;
    #pragma unroll
    for (int l = 0; l < 8; l++) sp += sw[r * 8 + l] * gr[l];
    redp[r][b] = sp;
    __syncthreads();    // covers sc + redp
    if (tid < 32) {
        float a = sse_b[0];
        #pragma unroll
        for (int rr = 0; rr < 8; rr++) a += redp[rr][tid];
        spat[tid] = sigmoidf(a);
    }
    __syncthreads();

    // y row r and first-pass IDCT: tm[j] = sum_l y[l] * D[l][j]
    float spb = spat[b];
    float tm[8];
    #pragma unroll
    for (int j = 0; j < 8; j++) tm[j] = 0.f;
    #pragma unroll
    for (int l = 0; l < 8; l++) {
        float v = gr[l];
        float y = fmaxf(v * sc[r * 8 + l], v * spb);  // feat may be negative
        #pragma unroll
        for (int j = 0; j < 8; j++) tm[j] += y * Ds[l * 8 + j];
    }
    #pragma unroll
    for (int j = 0; j < 8; j++) tmls[b][r * 8 + j] = tm[j];
    __syncthreads();

    // out row r of block b: o[j] = sum_k D[k][r] * tm[k][j]
    float o[8];
    #pragma unroll
    for (int j = 0; j < 8; j++) o[j] = 0.f;
    #pragma unroll
    for (int k = 0; k < 8; k++) {
        float d = Ds[k * 8 + r];
        #pragma unroll
        for (int j = 0; j < 8; j++) o[j] += d * tmls[b][k * 8 + j];
    }
    // direct coalesced write: plane row tg*8+r, cols b*8..b*8+7.
    // per wave: lanes cover contiguous 2 KB (b consecutive, 32 B each).
    float4* dst = (float4*)(plane + tg * 2048 + r * 256 + b * 8);
    dst[0] = make_float4(o[0], o[1], o[2], o[3]);
    dst[1] = make_float4(o[4], o[5], o[6], o[7]);
}

// Pure broadcast fan-out: wg = ig*32 + tg. Reads this tg's 8 KB stripe of the
// plane (L2/L3-resident) and streams it to 6 images with nontemporal float4
// stores. No barriers, no LDS, no math -> should run at fill-level write BW.
__global__ __launch_bounds__(256) void bcast_kernel(const float* __restrict__ plane,
                                                    float* __restrict__ out,
                                                    int nimg) {
    int tid = threadIdx.x;
    int tg = blockIdx.x & 31;
    int ig = blockIdx.x >> 5;

    const f32x4* src = (const f32x4*)(plane + tg * 2048);
    f32x4 w0 = src[tid];
    f32x4 w1 = src[tid + 256];
    #pragma unroll
    for (int m = 0; m < 6; m++) {
        int img = ig * 6 + m;
        if (img < nimg) {
            f32x4* dst = (f32x4*)(out + (size_t)img * 65536 + tg * 2048);
            __builtin_nontemporal_store(w0, dst + tid);
            __builtin_nontemporal_store(w1, dst + tid + 256);
        }
    }
}

extern "C" void kernel_launch(void* const* d_in, const int* in_sizes, int n_in,
                              void* d_out, int out_size, void* d_ws, size_t ws_size,
                              hipStream_t stream) {
    const float* x     = (const float*)d_in[0];
    const float* fc1_w = (const float*)d_in[1];
    const float* fc1_b = (const float*)d_in[2];
    const float* fc2_w = (const float*)d_in[3];
    const float* fc2_b = (const float*)d_in[4];
    const float* sse_w = (const float*)d_in[5];
    const float* sse_b = (const float*)d_in[6];
    float* ws = (float*)d_ws;
    float* feat  = ws + WS_FEAT;
    float* gpart = ws + WS_GPART;
    float* plane = ws + WS_PLANE;
    float* out = (float*)d_out;
    int nimg = out_size / 65536;   // 192 for bs=64

    dct_kernel<<<32, 256, 0, stream>>>(x, feat, gpart);
    plane_kernel<<<32, 256, 0, stream>>>(feat, gpart, fc1_w, fc1_b,
                                         fc2_w, fc2_b, sse_w, sse_b, plane);
    int ngrp = (nimg + 5) / 6;
    bcast_kernel<<<ngrp * 32, 256, 0, stream>>>(plane, out, nimg);
}